// Round 1
// baseline (263.617 us; speedup 1.0000x reference)
//
#include <hip/hip_runtime.h>
#include <hip/hip_bf16.h>

// Problem constants (fixed by the reference).
#define BB 32
#define SS 256
#define DD 256
#define UU 256
#define LL 16
#define DEG 16
#define NN (BB * SS)   // 8192 nodes
#define EE (NN * DEG)  // 131072 edges per branch

using short8 = __attribute__((ext_vector_type(8))) short;  // 8 bf16 (4 VGPRs)
using f32x4  = __attribute__((ext_vector_type(4))) float;  // MFMA accumulator

// ---------------------------------------------------------------------------
// K1: x[n,d] = src[s,b,d] (n = b*S+s), cast to bf16; gate dots in fp32.
// One block per node, 256 threads (d = tid).
// ---------------------------------------------------------------------------
__global__ __launch_bounds__(256) void k_prep(
    const float* __restrict__ src, const float* __restrict__ gin,
    const float* __restrict__ gout, const float* __restrict__ gloop,
    __hip_bfloat16* __restrict__ x_bf, float* __restrict__ xg_in,
    float* __restrict__ xg_out, float* __restrict__ xg_loop) {
  int n = blockIdx.x;
  int b = n / SS, s = n % SS;
  int d = threadIdx.x;
  float v = src[(size_t)(s * BB + b) * DD + d];
  x_bf[(size_t)n * DD + d] = __float2bfloat16(v);
  float p0 = v * gin[d], p1 = v * gout[d], p2 = v * gloop[d];
#pragma unroll
  for (int o = 32; o > 0; o >>= 1) {  // wave64 reduce
    p0 += __shfl_down(p0, o);
    p1 += __shfl_down(p1, o);
    p2 += __shfl_down(p2, o);
  }
  __shared__ float r0[4], r1[4], r2[4];
  int w = threadIdx.x >> 6, lane = threadIdx.x & 63;
  if (lane == 0) { r0[w] = p0; r1[w] = p1; r2[w] = p2; }
  __syncthreads();
  if (threadIdx.x == 0) {
    xg_in[n]   = r0[0] + r0[1] + r0[2] + r0[3];
    xg_out[n]  = r1[0] + r1[1] + r1[2] + r1[3];
    xg_loop[n] = r2[0] + r2[1] + r2[2] + r2[3];
  }
}

// ---------------------------------------------------------------------------
// K2: transpose+cast weights: Vt[l][u][d] = V[l][d][u] (bf16). z selects matrix.
// ---------------------------------------------------------------------------
__global__ void k_transpose(const float* __restrict__ Vin,
                            const float* __restrict__ Vout,
                            const float* __restrict__ Wself,
                            __hip_bfloat16* __restrict__ Vt_in,
                            __hip_bfloat16* __restrict__ Vt_out,
                            __hip_bfloat16* __restrict__ Wt_self) {
  __shared__ float t[32][33];
  int z = blockIdx.z;
  const float* srcM;
  __hip_bfloat16* dstM;
  if (z < LL)           { srcM = Vin  + (size_t)z        * DD * UU; dstM = Vt_in  + (size_t)z        * UU * DD; }
  else if (z < 2 * LL)  { srcM = Vout + (size_t)(z - LL) * DD * UU; dstM = Vt_out + (size_t)(z - LL) * UU * DD; }
  else                  { srcM = Wself;                              dstM = Wt_self; }
  int u0 = blockIdx.x * 32, d0 = blockIdx.y * 32;
  int tx = threadIdx.x, ty = threadIdx.y;
#pragma unroll
  for (int i = 0; i < 4; i++) {
    int dr = ty + i * 8;
    t[dr][tx] = srcM[(size_t)(d0 + dr) * UU + u0 + tx];
  }
  __syncthreads();
#pragma unroll
  for (int i = 0; i < 4; i++) {
    int ur = ty + i * 8;
    dstM[(size_t)(u0 + ur) * DD + d0 + tx] = __float2bfloat16(t[tx][ur]);
  }
}

// ---------------------------------------------------------------------------
// K3: bf16 MFMA GEMM. C[m,u] = sum_k A[m,k] * Bt[u,k]; A=[8192,256], Bt=[256,256]
// per blockIdx.z matrix. 128x128 tile, 4 waves in 2x2, each 4x4 of 16x16x32.
// Output bf16. ldB/ldC stride per z (batched over labels).
// ---------------------------------------------------------------------------
#define Bb 128
#define BK 32
#define LDSS 40  // padded row stride (elements): 80 B, 16B-aligned, 2-way banks (free)

__global__ __launch_bounds__(256) void k_gemm(
    const __hip_bfloat16* __restrict__ A, const __hip_bfloat16* __restrict__ Bt_base,
    __hip_bfloat16* __restrict__ Cbase, int ldBmat, int ldCmat) {
  __shared__ __hip_bfloat16 As[Bb * LDSS];
  __shared__ __hip_bfloat16 Bs[Bb * LDSS];
  const __hip_bfloat16* Bt = Bt_base + (size_t)blockIdx.z * ldBmat;
  __hip_bfloat16* C = Cbase + (size_t)blockIdx.z * ldCmat;
  int row0 = blockIdx.x * Bb, col0 = blockIdx.y * Bb;
  int tid = threadIdx.x;
  int w = tid >> 6, lane = tid & 63;
  int wr = (w >> 1) * 64, wc = (w & 1) * 64;
  int lrow = lane & 15, quad = lane >> 4;

  f32x4 acc[4][4] = {};
  for (int k0 = 0; k0 < DD; k0 += BK) {
#pragma unroll
    for (int i = 0; i < 2; i++) {  // stage 128x32 bf16 tiles, 16B per load
      int linear = i * 256 + tid;      // 0..511
      int r = linear >> 2;             // 0..127
      int cs = (linear & 3) * 8;       // 0,8,16,24
      *(f32x4*)&As[r * LDSS + cs] = *(const f32x4*)&A[(size_t)(row0 + r) * DD + k0 + cs];
      *(f32x4*)&Bs[r * LDSS + cs] = *(const f32x4*)&Bt[(size_t)(col0 + r) * DD + k0 + cs];
    }
    __syncthreads();
    short8 af[4], bf[4];
#pragma unroll
    for (int i = 0; i < 4; i++)
      af[i] = *(const short8*)&As[(wr + i * 16 + lrow) * LDSS + quad * 8];
#pragma unroll
    for (int j = 0; j < 4; j++)
      bf[j] = *(const short8*)&Bs[(wc + j * 16 + lrow) * LDSS + quad * 8];
#pragma unroll
    for (int i = 0; i < 4; i++)
#pragma unroll
      for (int j = 0; j < 4; j++)
        acc[i][j] = __builtin_amdgcn_mfma_f32_16x16x32_bf16(af[i], bf[j], acc[i][j], 0, 0, 0);
    __syncthreads();
  }
  // C/D layout (verified m89/m91): col = lane&15, row = quad*4 + r
#pragma unroll
  for (int i = 0; i < 4; i++)
#pragma unroll
    for (int j = 0; j < 4; j++)
#pragma unroll
      for (int r = 0; r < 4; r++) {
        int row = row0 + wr + i * 16 + quad * 4 + r;
        int col = col0 + wc + j * 16 + lrow;
        C[(size_t)row * UU + col] = __float2bfloat16(acc[i][j][r]);
      }
}

// ---------------------------------------------------------------------------
// K4: res[n,u] = sigmoid(xg_loop[n]) * mask_loop[n] * same[n,u]  (init, no +=)
// ---------------------------------------------------------------------------
__global__ __launch_bounds__(256) void k_resinit(
    const __hip_bfloat16* __restrict__ same, const float* __restrict__ xg_loop,
    const float* __restrict__ mask_loop, float* __restrict__ res) {
  int n = blockIdx.x, u = threadIdx.x;
  float w = (1.f / (1.f + __expf(-xg_loop[n]))) * mask_loop[n];
  res[(size_t)n * UU + u] = w * __bfloat162float(same[(size_t)n * UU + u]);
}

// ---------------------------------------------------------------------------
// K5: scatter-accumulate one branch / label chunk. One block per dst node (no
// atomics: a block owns all 16 slots of its node).
// ---------------------------------------------------------------------------
__global__ __launch_bounds__(256) void k_scatter(
    const __hip_bfloat16* __restrict__ buf,  // [lc, N, U] bf16, labels l0..l1
    const float* __restrict__ bias,          // [L,U]
    const float* __restrict__ bgate,         // [L]
    const float* __restrict__ xg,            // [N]
    const int* __restrict__ arc0, const int* __restrict__ arc1,
    const int* __restrict__ lab, const float* __restrict__ mask,  // [N,16]
    float* __restrict__ res, int l0, int l1) {
  __shared__ int s_src[DEG];
  __shared__ int s_l[DEG];
  __shared__ float s_w[DEG];
  int n = blockIdx.x, u = threadIdx.x;
  if (u < DEG) {
    int e = n * DEG + u;
    int l = lab[e];
    int srcn = arc0[e] * SS + arc1[e];
    float wv = 0.f;
    if (l >= l0 && l < l1)
      wv = (1.f / (1.f + __expf(-(xg[srcn] + bgate[l])))) * mask[e];
    s_src[u] = srcn; s_l[u] = l; s_w[u] = wv;
  }
  __syncthreads();
  float acc = 0.f;
#pragma unroll
  for (int k = 0; k < DEG; k++) {
    float wv = s_w[k];
    if (wv != 0.f) {  // uniform across block (LDS value)
      const __hip_bfloat16* rowp = buf + ((size_t)(s_l[k] - l0) * NN + s_src[k]) * UU;
      acc += wv * (__bfloat162float(rowp[u]) + bias[s_l[k] * UU + u]);
    }
  }
  res[(size_t)n * UU + u] += acc;
}

// ---------------------------------------------------------------------------
// K6: out[s,b,u] = relu(res[b*S+s, u]) * sent_mask[s,b]
// ---------------------------------------------------------------------------
__global__ __launch_bounds__(256) void k_finish(const float* __restrict__ res,
                                                const float* __restrict__ sent,
                                                float* __restrict__ out) {
  int sb = blockIdx.x;  // s*B + b
  int s = sb / BB, b = sb % BB;
  int u = threadIdx.x;
  float v = res[((size_t)b * SS + s) * UU + u];
  v = v > 0.f ? v : 0.f;
  out[(size_t)sb * UU + u] = v * sent[sb];
}

extern "C" void kernel_launch(void* const* d_in, const int* in_sizes, int n_in,
                              void* d_out, int out_size, void* d_ws, size_t ws_size,
                              hipStream_t stream) {
  const float* src      = (const float*)d_in[0];
  const float* V_in     = (const float*)d_in[1];
  const float* b_in     = (const float*)d_in[2];
  const float* V_ing    = (const float*)d_in[3];
  const float* b_ing    = (const float*)d_in[4];
  const float* V_out    = (const float*)d_in[5];
  const float* b_out    = (const float*)d_in[6];
  const float* V_outg   = (const float*)d_in[7];
  const float* b_outg   = (const float*)d_in[8];
  const float* W_self   = (const float*)d_in[9];
  const float* W_selfg  = (const float*)d_in[10];
  const int* arc_in     = (const int*)d_in[11];
  const int* arc_out    = (const int*)d_in[12];
  const int* lab_in     = (const int*)d_in[13];
  const int* lab_out    = (const int*)d_in[14];
  const float* mask_in  = (const float*)d_in[15];
  const float* mask_out = (const float*)d_in[16];
  const float* mask_loop= (const float*)d_in[17];
  const float* sent     = (const float*)d_in[18];
  float* out = (float*)d_out;

  char* ws = (char*)d_ws;
  size_t off = 0;
  auto alloc = [&](size_t bytes) -> void* {
    void* p = ws + off;
    off += (bytes + 255) & ~(size_t)255;
    return p;
  };
  __hip_bfloat16* x_bf    = (__hip_bfloat16*)alloc((size_t)NN * DD * 2);
  __hip_bfloat16* Vt_in   = (__hip_bfloat16*)alloc((size_t)LL * UU * DD * 2);
  __hip_bfloat16* Vt_out  = (__hip_bfloat16*)alloc((size_t)LL * UU * DD * 2);
  __hip_bfloat16* Wt_self = (__hip_bfloat16*)alloc((size_t)UU * DD * 2);
  float* xg_in   = (float*)alloc(NN * 4);
  float* xg_out  = (float*)alloc(NN * 4);
  float* xg_loop = (float*)alloc(NN * 4);
  float* res     = (float*)alloc((size_t)NN * UU * 4);
  size_t remain = ws_size > off ? ws_size - off : 0;
  int C = 16;  // labels per chunk; shrink to fit ws (same every call: graph-safe)
  while (C > 1 && (size_t)C * NN * UU * 2 > remain) C >>= 1;
  __hip_bfloat16* buf = (__hip_bfloat16*)alloc((size_t)C * NN * UU * 2);

  k_prep<<<NN, 256, 0, stream>>>(src, V_ing, V_outg, W_selfg, x_bf, xg_in, xg_out, xg_loop);
  k_transpose<<<dim3(UU / 32, DD / 32, 2 * LL + 1), dim3(32, 8), 0, stream>>>(
      V_in, V_out, W_self, Vt_in, Vt_out, Wt_self);

  // self-loop branch: same = x @ W_self; res = sigmoid(xg_loop)*mask_loop*same
  k_gemm<<<dim3(NN / 128, UU / 128, 1), 256, 0, stream>>>(x_bf, Wt_self, buf, 0, 0);
  k_resinit<<<NN, 256, 0, stream>>>(buf, xg_loop, mask_loop, res);

  for (int br = 0; br < 2; br++) {
    const __hip_bfloat16* Vt = br ? Vt_out : Vt_in;
    const float* bias = br ? b_out : b_in;
    const float* bg   = br ? b_outg : b_ing;
    const float* xg   = br ? xg_out : xg_in;
    const int* a0     = br ? arc_out : arc_in;
    const int* a1     = a0 + EE;
    const int* lb     = br ? lab_out : lab_in;
    const float* mk   = br ? mask_out : mask_in;
    for (int l0 = 0; l0 < LL; l0 += C) {
      int lc = (LL - l0) < C ? (LL - l0) : C;
      k_gemm<<<dim3(NN / 128, UU / 128, lc), 256, 0, stream>>>(
          x_bf, Vt + (size_t)l0 * UU * DD, buf, UU * DD, NN * UU);
      k_scatter<<<NN, 256, 0, stream>>>(buf, bias, bg, xg, a0, a1, lb, mk, res,
                                        l0, l0 + lc);
    }
  }
  k_finish<<<NN, 256, 0, stream>>>(res, sent, out);
}

// Round 2
// 196.337 us; speedup vs baseline: 1.3427x; 1.3427x over previous
//
#include <hip/hip_runtime.h>
#include <hip/hip_bf16.h>

// Problem constants (fixed by the reference).
#define BB 32
#define SS 256
#define DD 256
#define UU 256
#define LL 16
#define DEG 16
#define NN (BB * SS)   // 8192 nodes
#define EE (NN * DEG)  // 131072 edges per branch
#define NSLICE 33      // slice 0 = self-loop, 1..16 = in labels, 17..32 = out labels

using short8 = __attribute__((ext_vector_type(8))) short;  // 8 bf16 (4 VGPRs)
using f32x4  = __attribute__((ext_vector_type(4))) float;  // MFMA accumulator

// async global->LDS, 16B per lane, LDS dest = wave-uniform base + lane*16
#define GLDS(g, l)                                                        \
  __builtin_amdgcn_global_load_lds(                                       \
      (const __attribute__((address_space(1))) void*)(g),                 \
      (__attribute__((address_space(3))) void*)(l), 16, 0, 0)

__device__ __forceinline__ float bf2f(unsigned short v) {
  union { unsigned u; float f; } t;
  t.u = ((unsigned)v) << 16;
  return t.f;
}

// ---------------------------------------------------------------------------
// K1: x[n,d] = src[s,b,d] (n = b*S+s), cast to bf16; 3 gate dots in fp32.
// ---------------------------------------------------------------------------
__global__ __launch_bounds__(256) void k_prep(
    const float* __restrict__ src, const float* __restrict__ gin,
    const float* __restrict__ gout, const float* __restrict__ gloop,
    __hip_bfloat16* __restrict__ x_bf, float* __restrict__ xg_in,
    float* __restrict__ xg_out, float* __restrict__ xg_loop) {
  int n = blockIdx.x;
  int b = n / SS, s = n % SS;
  int d = threadIdx.x;
  float v = src[(size_t)(s * BB + b) * DD + d];
  x_bf[(size_t)n * DD + d] = __float2bfloat16(v);
  float p0 = v * gin[d], p1 = v * gout[d], p2 = v * gloop[d];
#pragma unroll
  for (int o = 32; o > 0; o >>= 1) {
    p0 += __shfl_down(p0, o);
    p1 += __shfl_down(p1, o);
    p2 += __shfl_down(p2, o);
  }
  __shared__ float r0[4], r1[4], r2[4];
  int w = threadIdx.x >> 6, lane = threadIdx.x & 63;
  if (lane == 0) { r0[w] = p0; r1[w] = p1; r2[w] = p2; }
  __syncthreads();
  if (threadIdx.x == 0) {
    xg_in[n]   = r0[0] + r0[1] + r0[2] + r0[3];
    xg_out[n]  = r1[0] + r1[1] + r1[2] + r1[3];
    xg_loop[n] = r2[0] + r2[1] + r2[2] + r2[3];
  }
}

// ---------------------------------------------------------------------------
// K2: transpose+cast all 33 weight matrices into Vt[slice][u][d] (bf16).
// slice 0 = W_self, 1..16 = V_in, 17..32 = V_out.
// ---------------------------------------------------------------------------
__global__ void k_transpose(const float* __restrict__ Vin,
                            const float* __restrict__ Vout,
                            const float* __restrict__ Wself,
                            __hip_bfloat16* __restrict__ Vt) {
  __shared__ float t[32][33];
  int z = blockIdx.z;
  const float* srcM = (z == 0) ? Wself
                    : (z <= LL ? Vin  + (size_t)(z - 1)      * DD * UU
                               : Vout + (size_t)(z - 1 - LL) * DD * UU);
  __hip_bfloat16* dstM = Vt + (size_t)z * UU * DD;
  int u0 = blockIdx.x * 32, d0 = blockIdx.y * 32;
  int tx = threadIdx.x, ty = threadIdx.y;
#pragma unroll
  for (int i = 0; i < 4; i++) {
    int dr = ty + i * 8;
    t[dr][tx] = srcM[(size_t)(d0 + dr) * UU + u0 + tx];
  }
  __syncthreads();
#pragma unroll
  for (int i = 0; i < 4; i++) {
    int ur = ty + i * 8;
    dstM[(size_t)(u0 + ur) * DD + d0 + tx] = __float2bfloat16(t[tx][ur]);
  }
}

// ---------------------------------------------------------------------------
// K3: bf16 MFMA GEMM, m97 structure: global_load_lds width=16, unpadded LDS.
// C[slice][m][u] = sum_k A[m][k] * Vt[slice][u][k]  (+ bias[slice][u]).
// 128x128 tile, BK=32, 4 waves 2x2, each 4x4 frags of 16x16x32 bf16.
// ---------------------------------------------------------------------------
__global__ __launch_bounds__(256) void k_gemm(
    const __hip_bfloat16* __restrict__ A, const __hip_bfloat16* __restrict__ Vt,
    const float* __restrict__ b_in, const float* __restrict__ b_out,
    __hip_bfloat16* __restrict__ buf, int z0) {
  __shared__ __align__(16) __hip_bfloat16 As[128 * 32];
  __shared__ __align__(16) __hip_bfloat16 Bs[128 * 32];
  int slice = z0 + blockIdx.z;
  const __hip_bfloat16* Bt = Vt + (size_t)slice * UU * DD;
  __hip_bfloat16* C = buf + (size_t)blockIdx.z * NN * UU;
  const float* bias = nullptr;
  if (slice >= 1 && slice <= LL) bias = b_in + (size_t)(slice - 1) * UU;
  else if (slice > LL)           bias = b_out + (size_t)(slice - 1 - LL) * UU;

  int row0 = blockIdx.x * 128, col0 = blockIdx.y * 128;
  int tid = threadIdx.x;
  int w = tid >> 6, lane = tid & 63;
  int wr = (w >> 1) * 64, wc = (w & 1) * 64;
  int lrow = lane & 15, quad = lane >> 4;
  int sr = lane >> 2;          // staging: row within 16-row group
  int sc = (lane & 3) * 8;     // staging: k-offset (elements)

  f32x4 acc[4][4] = {};
  for (int k0 = 0; k0 < DD; k0 += 32) {
#pragma unroll
    for (int t = 0; t < 2; t++) {
      int rb = (w * 2 + t) * 16;  // wave-uniform 16-row group
      GLDS(&A[(size_t)(row0 + rb + sr) * DD + k0 + sc], &As[rb * 32]);
      GLDS(&Bt[(size_t)(col0 + rb + sr) * DD + k0 + sc], &Bs[rb * 32]);
    }
    __syncthreads();  // compiler drains vmcnt before s_barrier
    short8 af[4], bfr[4];
#pragma unroll
    for (int i = 0; i < 4; i++)
      af[i] = *(const short8*)&As[(wr + i * 16 + lrow) * 32 + quad * 8];
#pragma unroll
    for (int j = 0; j < 4; j++)
      bfr[j] = *(const short8*)&Bs[(wc + j * 16 + lrow) * 32 + quad * 8];
#pragma unroll
    for (int i = 0; i < 4; i++)
#pragma unroll
      for (int j = 0; j < 4; j++)
        acc[i][j] = __builtin_amdgcn_mfma_f32_16x16x32_bf16(af[i], bfr[j], acc[i][j], 0, 0, 0);
    __syncthreads();
  }
  // C/D layout (m89/m91): col = lane&15, row = quad*4 + r
#pragma unroll
  for (int j = 0; j < 4; j++) {
    int col = col0 + wc + j * 16 + lrow;
    float bv = bias ? bias[col] : 0.f;
#pragma unroll
    for (int i = 0; i < 4; i++) {
      int rowb = row0 + wr + i * 16 + quad * 4;
#pragma unroll
      for (int r = 0; r < 4; r++)
        C[(size_t)(rowb + r) * UU + col] = __float2bfloat16(acc[i][j][r] + bv);
    }
  }
}

// ---------------------------------------------------------------------------
// K4 (fused path): per dst node, gather 33 slices, gate, sum, relu, sent_mask,
// write out directly. 64 threads, 4 u's each (ushort4/float4).
// ---------------------------------------------------------------------------
__global__ __launch_bounds__(64) void k_fuse(
    const __hip_bfloat16* __restrict__ buf,
    const float* __restrict__ b_ing, const float* __restrict__ b_outg,
    const float* __restrict__ xg_in, const float* __restrict__ xg_out,
    const float* __restrict__ xg_loop,
    const int* __restrict__ arc_in, const int* __restrict__ arc_out,
    const int* __restrict__ lab_in, const int* __restrict__ lab_out,
    const float* __restrict__ mask_in, const float* __restrict__ mask_out,
    const float* __restrict__ mask_loop, const float* __restrict__ sent,
    float* __restrict__ out) {
  __shared__ int s_src[32];
  __shared__ int s_slice[32];
  __shared__ float s_w[32];
  int n = blockIdx.x, tid = threadIdx.x;
  if (tid < 32) {
    int br = tid >> 4, k = tid & 15;
    int e = n * DEG + k;
    const int* a = br ? arc_out : arc_in;
    int l = (br ? lab_out : lab_in)[e];
    int srcn = a[e] * SS + a[EE + e];
    float g = (br ? xg_out : xg_in)[srcn] + (br ? b_outg : b_ing)[l];
    float wv = (1.f / (1.f + __expf(-g))) * (br ? mask_out : mask_in)[e];
    s_src[tid] = srcn;
    s_slice[tid] = 1 + br * LL + l;
    s_w[tid] = wv;
  }
  __syncthreads();
  int u4 = tid * 4;
  float a0, a1, a2, a3;
  {
    float wl = (1.f / (1.f + __expf(-xg_loop[n]))) * mask_loop[n];
    ushort4 v = *(const ushort4*)&buf[(size_t)n * UU + u4];
    a0 = wl * bf2f(v.x); a1 = wl * bf2f(v.y);
    a2 = wl * bf2f(v.z); a3 = wl * bf2f(v.w);
  }
#pragma unroll
  for (int k = 0; k < 32; k++) {
    float wv = s_w[k];
    ushort4 v = *(const ushort4*)&buf[((size_t)s_slice[k] * NN + s_src[k]) * UU + u4];
    a0 += wv * bf2f(v.x); a1 += wv * bf2f(v.y);
    a2 += wv * bf2f(v.z); a3 += wv * bf2f(v.w);
  }
  int s = n % SS, b = n / SS;
  float sm = sent[s * BB + b];
  float4 o;
  o.x = fmaxf(a0, 0.f) * sm; o.y = fmaxf(a1, 0.f) * sm;
  o.z = fmaxf(a2, 0.f) * sm; o.w = fmaxf(a3, 0.f) * sm;
  *(float4*)&out[((size_t)s * BB + b) * UU + u4] = o;
}

// ---------------------------------------------------------------------------
// Fallback path kernels (only if ws can't hold 33 slices; ws is 256 MiB so
// normally unused, but kept for safety).
// ---------------------------------------------------------------------------
__global__ __launch_bounds__(64) void k_resinit(
    const __hip_bfloat16* __restrict__ bufS, const float* __restrict__ xg_loop,
    const float* __restrict__ mask_loop, float* __restrict__ res) {
  int n = blockIdx.x, u4 = threadIdx.x * 4;
  float wl = (1.f / (1.f + __expf(-xg_loop[n]))) * mask_loop[n];
  ushort4 v = *(const ushort4*)&bufS[(size_t)n * UU + u4];
  float4 r;
  r.x = wl * bf2f(v.x); r.y = wl * bf2f(v.y);
  r.z = wl * bf2f(v.z); r.w = wl * bf2f(v.w);
  *(float4*)&res[(size_t)n * UU + u4] = r;
}

__global__ __launch_bounds__(64) void k_scatter_acc(
    const __hip_bfloat16* __restrict__ buf,
    const float* __restrict__ b_ing, const float* __restrict__ b_outg,
    const float* __restrict__ xg_in, const float* __restrict__ xg_out,
    const int* __restrict__ arc_in, const int* __restrict__ arc_out,
    const int* __restrict__ lab_in, const int* __restrict__ lab_out,
    const float* __restrict__ mask_in, const float* __restrict__ mask_out,
    float* __restrict__ res, int c0, int c1) {
  __shared__ int s_src[32];
  __shared__ int s_slice[32];
  __shared__ float s_w[32];
  int n = blockIdx.x, tid = threadIdx.x;
  if (tid < 32) {
    int br = tid >> 4, k = tid & 15;
    int e = n * DEG + k;
    const int* a = br ? arc_out : arc_in;
    int l = (br ? lab_out : lab_in)[e];
    int srcn = a[e] * SS + a[EE + e];
    float g = (br ? xg_out : xg_in)[srcn] + (br ? b_outg : b_ing)[l];
    float wv = (1.f / (1.f + __expf(-g))) * (br ? mask_out : mask_in)[e];
    int sl = 1 + br * LL + l;
    s_src[tid] = srcn;
    s_slice[tid] = sl;
    s_w[tid] = (sl >= c0 && sl < c1) ? wv : 0.f;
  }
  __syncthreads();
  int u4 = tid * 4;
  float a0 = 0, a1 = 0, a2 = 0, a3 = 0;
  for (int k = 0; k < 32; k++) {
    float wv = s_w[k];
    if (wv != 0.f) {
      ushort4 v = *(const ushort4*)&buf[((size_t)(s_slice[k] - c0) * NN + s_src[k]) * UU + u4];
      a0 += wv * bf2f(v.x); a1 += wv * bf2f(v.y);
      a2 += wv * bf2f(v.z); a3 += wv * bf2f(v.w);
    }
  }
  float4* rp = (float4*)&res[(size_t)n * UU + u4];
  float4 r = *rp;
  r.x += a0; r.y += a1; r.z += a2; r.w += a3;
  *rp = r;
}

__global__ __launch_bounds__(64) void k_finish(const float* __restrict__ res,
                                               const float* __restrict__ sent,
                                               float* __restrict__ out) {
  int n = blockIdx.x, u4 = threadIdx.x * 4;
  int s = n % SS, b = n / SS;
  float sm = sent[s * BB + b];
  float4 v = *(const float4*)&res[(size_t)n * UU + u4];
  float4 o;
  o.x = fmaxf(v.x, 0.f) * sm; o.y = fmaxf(v.y, 0.f) * sm;
  o.z = fmaxf(v.z, 0.f) * sm; o.w = fmaxf(v.w, 0.f) * sm;
  *(float4*)&out[((size_t)s * BB + b) * UU + u4] = o;
}

extern "C" void kernel_launch(void* const* d_in, const int* in_sizes, int n_in,
                              void* d_out, int out_size, void* d_ws, size_t ws_size,
                              hipStream_t stream) {
  const float* src      = (const float*)d_in[0];
  const float* V_in     = (const float*)d_in[1];
  const float* b_in     = (const float*)d_in[2];
  const float* V_ing    = (const float*)d_in[3];
  const float* b_ing    = (const float*)d_in[4];
  const float* V_out    = (const float*)d_in[5];
  const float* b_out    = (const float*)d_in[6];
  const float* V_outg   = (const float*)d_in[7];
  const float* b_outg   = (const float*)d_in[8];
  const float* W_self   = (const float*)d_in[9];
  const float* W_selfg  = (const float*)d_in[10];
  const int* arc_in     = (const int*)d_in[11];
  const int* arc_out    = (const int*)d_in[12];
  const int* lab_in     = (const int*)d_in[13];
  const int* lab_out    = (const int*)d_in[14];
  const float* mask_in  = (const float*)d_in[15];
  const float* mask_out = (const float*)d_in[16];
  const float* mask_loop= (const float*)d_in[17];
  const float* sent     = (const float*)d_in[18];
  float* out = (float*)d_out;

  char* ws = (char*)d_ws;
  size_t off = 0;
  auto alloc = [&](size_t bytes) -> void* {
    void* p = ws + off;
    off += (bytes + 255) & ~(size_t)255;
    return p;
  };
  __hip_bfloat16* x_bf = (__hip_bfloat16*)alloc((size_t)NN * DD * 2);
  __hip_bfloat16* Vt   = (__hip_bfloat16*)alloc((size_t)NSLICE * UU * DD * 2);
  float* xg_in   = (float*)alloc(NN * 4);
  float* xg_out  = (float*)alloc(NN * 4);
  float* xg_loop = (float*)alloc(NN * 4);

  const size_t slice_b = (size_t)NN * UU * 2;
  size_t remain = ws_size > off ? ws_size - off : 0;

  k_prep<<<NN, 256, 0, stream>>>(src, V_ing, V_outg, W_selfg, x_bf, xg_in, xg_out, xg_loop);
  k_transpose<<<dim3(UU / 32, DD / 32, NSLICE), dim3(32, 8), 0, stream>>>(
      V_in, V_out, W_self, Vt);

  if (remain >= NSLICE * slice_b) {
    // Fused path: one GEMM launch over all 33 slices, one gather/epilogue.
    __hip_bfloat16* buf = (__hip_bfloat16*)alloc(NSLICE * slice_b);
    k_gemm<<<dim3(NN / 128, UU / 128, NSLICE), 256, 0, stream>>>(
        x_bf, Vt, b_in, b_out, buf, 0);
    k_fuse<<<NN, 64, 0, stream>>>(buf, b_ing, b_outg, xg_in, xg_out, xg_loop,
                                  arc_in, arc_out, lab_in, lab_out,
                                  mask_in, mask_out, mask_loop, sent, out);
  } else {
    // Chunked fallback.
    float* res = (float*)alloc((size_t)NN * UU * 4);
    __hip_bfloat16* bufS = (__hip_bfloat16*)alloc(slice_b);
    size_t rem2 = ws_size > off ? ws_size - off : 0;
    int C = (int)(rem2 / slice_b);
    if (C > 32) C = 32;
    if (C < 1) C = 1;  // ws too small to be usable; assume never
    __hip_bfloat16* bufC = (__hip_bfloat16*)alloc((size_t)C * slice_b);

    k_gemm<<<dim3(NN / 128, UU / 128, 1), 256, 0, stream>>>(
        x_bf, Vt, b_in, b_out, bufS, 0);
    k_resinit<<<NN, 64, 0, stream>>>(bufS, xg_loop, mask_loop, res);
    for (int c0 = 1; c0 < NSLICE; c0 += C) {
      int lc = NSLICE - c0 < C ? NSLICE - c0 : C;
      k_gemm<<<dim3(NN / 128, UU / 128, lc), 256, 0, stream>>>(
          x_bf, Vt, b_in, b_out, bufC, c0);
      k_scatter_acc<<<NN, 64, 0, stream>>>(bufC, b_ing, b_outg, xg_in, xg_out,
                                           arc_in, arc_out, lab_in, lab_out,
                                           mask_in, mask_out, res, c0, c0 + lc);
    }
    k_finish<<<NN, 64, 0, stream>>>(res, sent, out);
  }
}